// Round 1
// baseline (182161.792 us; speedup 1.0000x reference)
//
#include <hip/hip_runtime.h>

// DNADecoder: B=64,T=128,P=1024,D=512,F=2048,V=4096,L=4
// Persistent-kernel version: the whole 128-step decode runs in ONE kernel
// (512 wgs x 256 thr, guaranteed co-resident: LDS 45KB -> 3 wg/CU capacity,
// launch_bounds(256,2) -> VGPR<=256 -> 8 waves/CU; grid 512 = 2 wg/CU).
// Grid-wide sync via distributed-slot barrier + agent-scope fences.
// Math identical to the previous multi-kernel version.

#define B 64
#define T 128
#define PP 1024
#define D 512
#define F 2048
#define V 4096
#define XP 20       // padded row-stride (floats) for transposed LDS tiles
#define NWG 512     // persistent grid size (2 wgs per CU on 256 CUs)

typedef const float* fp;

static __device__ __forceinline__ float wred(float s){
    #pragma unroll
    for (int o = 32; o > 0; o >>= 1) s += __shfl_xor(s, o, 64);
    return s;
}

// ---------------- grid barrier: 64 slots, 128B apart; monotonic counters ----
// arrival: one agent-release fetch_add per wg. wait: wave0 gathers all 64
// slots (one load per lane), shfl-reduces, compares against 512*phase.
static __device__ __forceinline__ void gsync(unsigned* bar, unsigned ph){
    __syncthreads();
    int tid = threadIdx.x;
    if (tid == 0){
        __builtin_amdgcn_fence(__ATOMIC_RELEASE, "agent");
        __hip_atomic_fetch_add(&bar[(blockIdx.x & 63) << 5], 1u,
                               __ATOMIC_RELAXED, __HIP_MEMORY_SCOPE_AGENT);
    }
    if (tid < 64){
        unsigned tgt = ph * (unsigned)NWG;
        for (;;){
            unsigned v = __hip_atomic_load(&bar[tid << 5],
                                           __ATOMIC_RELAXED, __HIP_MEMORY_SCOPE_AGENT);
            #pragma unroll
            for (int o = 32; o > 0; o >>= 1) v += __shfl_xor(v, o, 64);
            if (v >= tgt) break;
            __builtin_amdgcn_s_sleep(2);
        }
        __builtin_amdgcn_fence(__ATOMIC_ACQUIRE, "agent");
    }
    __syncthreads();
}

__global__ void k_init(unsigned* bar){
    bar[blockIdx.x * 256 + threadIdx.x] = 0u;
}

// ---------------- setup: protein -> mem1 -> per-layer cross-attn constant ----
__global__ __launch_bounds__(256) void k_setup_mem(
    fp prot, fp p1w, fp p1b, fp p2w, fp p2b,
    fp caw, fp cab, float* ca_out)
{
    __shared__ float xp[PP];
    __shared__ float hr[PP];
    __shared__ float m1[D];
    __shared__ float tv[D];
    int b = blockIdx.x, tid = threadIdx.x;
    for (int i = tid; i < PP; i += 256) xp[i] = prot[b*PP + i];
    __syncthreads();
    for (int c = tid; c < 1024; c += 256){
        float acc = p1b[c];
        for (int k = 0; k < PP; k++) acc = fmaf(xp[k], p1w[k*1024 + c], acc);
        hr[c] = fmaxf(acc, 0.f);
    }
    __syncthreads();
    for (int c = tid; c < D; c += 256){
        float acc = p2b[c];
        for (int k = 0; k < 1024; k++) acc = fmaf(hr[k], p2w[k*D + c], acc);
        m1[c] = acc;
    }
    __syncthreads();
    for (int l = 0; l < 4; l++){
        const float* wv = caw + (size_t)(l*4 + 2)*D*D;
        const float* bv = cab + (l*4 + 2)*D;
        for (int c = tid; c < D; c += 256){
            float acc = bv[c];
            for (int k = 0; k < D; k++) acc = fmaf(m1[k], wv[k*D + c], acc);
            tv[c] = acc;
        }
        __syncthreads();
        const float* wo = caw + (size_t)(l*4 + 3)*D*D;
        const float* bo = cab + (l*4 + 3)*D;
        for (int c = tid; c < D; c += 256){
            float acc = bo[c];
            for (int k = 0; k < D; k++) acc = fmaf(tv[k], wo[k*D + c], acc);
            ca_out[(l*B + b)*D + c] = acc;
        }
        __syncthreads();
    }
}

// ---------------- setup: fold self-attn  Wfold = Wv@Wo + I, bfold = bv@Wo+bo --
__global__ __launch_bounds__(256) void k_fold_sa(
    fp saw, fp sab, float* wfold, float* bfold)
{
    int l = blockIdx.x >> 6;
    int kb = blockIdx.x & 63;              // 8 rows of Wfold each
    int tid = threadIdx.x;
    const float* Wv = saw + (size_t)(l*4 + 2)*D*D;
    const float* Wo = saw + (size_t)(l*4 + 3)*D*D;
    __shared__ float a[8][D];
    for (int i = tid; i < 8*D; i += 256){
        int r = i >> 9, m = i & 511;
        a[r][m] = Wv[(kb*8 + r)*D + m];
    }
    __syncthreads();
    for (int cc = 0; cc < 2; cc++){
        int c = tid + cc*256;
        float acc[8];
        #pragma unroll
        for (int r = 0; r < 8; r++) acc[r] = 0.f;
        for (int m = 0; m < D; m++){
            float w = Wo[m*D + c];
            #pragma unroll
            for (int r = 0; r < 8; r++) acc[r] = fmaf(a[r][m], w, acc[r]);
        }
        #pragma unroll
        for (int r = 0; r < 8; r++){
            int kg = kb*8 + r;
            wfold[((size_t)l*D + kg)*D + c] = acc[r] + (kg == c ? 1.f : 0.f);
        }
    }
    if (kb == 0){
        const float* bv = sab + (l*4 + 2)*D;
        const float* bo = sab + (l*4 + 3)*D;
        for (int c = tid; c < D; c += 256){
            float acc = bo[c];
            for (int m = 0; m < D; m++) acc = fmaf(bv[m], Wo[m*D + c], acc);
            bfold[l*D + c] = acc;
        }
    }
}

// ---------- prologues: build transposed padded LDS x^T tile for 16 rows -------
static __device__ void pro_emb(float* xt, const int* tok, fp emb, fp pe,
                               int t, int r0, int d0, int tid)
{
    int lane = tid & 63, wid = tid >> 6;
    for (int i = 0; i < 4; i++){
        int rr = wid*4 + i;
        int tk = tok[r0 + rr];
        const float* er = emb + (size_t)tk*D + d0;
        const float* pr = pe + t*D + d0;
        #pragma unroll
        for (int j = 0; j < 4; j++){
            int d = lane + j*64;
            xt[d*XP + rr] = er[d] + pr[d];
        }
    }
}

static __device__ void pro_ln4(float* xt, const float* u3, fp g, fp bb,
                               int r0, int d0, int tid)
{
    int lane = tid & 63, wid = tid >> 6;
    int jb = d0 >> 6;
    for (int i = 0; i < 4; i++){
        int rr = wid*4 + i, r = r0 + rr;
        float e[8]; float s = 0.f, sq = 0.f;
        #pragma unroll
        for (int j = 0; j < 8; j++){
            int d = lane + j*64;
            float v = u3[r*D + d] + u3[B*D + r*D + d]
                    + u3[2*B*D + r*D + d] + u3[3*B*D + r*D + d];
            e[j] = v; s += v; sq += v*v;
        }
        s = wred(s); sq = wred(sq);
        float mu = s*(1.f/D);
        float rs = rsqrtf(sq*(1.f/D) - mu*mu + 1e-5f);
        #pragma unroll
        for (int j = 0; j < 8; j++){
            int d = lane + j*64;
            if (j >= jb && j < jb + 4)
                xt[(d - d0)*XP + rr] = (e[j]-mu)*rs*g[d] + bb[d];
        }
    }
}

static __device__ void pro_ln2(float* xt, float* zc, const float* u1, const float* ca,
                               fp g0, fp b0, fp g1, fp b1,
                               int r0, int d0, int c0, int tid)
{
    int lane = tid & 63, wid = tid >> 6;
    int jb = d0 >> 6, jc = c0 >> 6;
    for (int i = 0; i < 4; i++){
        int rr = wid*4 + i, r = r0 + rr;
        float e[8]; float s = 0.f, sq = 0.f;
        #pragma unroll
        for (int j = 0; j < 8; j++){
            int d = lane + j*64;
            float v = u1[r*D + d] + u1[B*D + r*D + d];
            e[j] = v; s += v; sq += v*v;
        }
        s = wred(s); sq = wred(sq);
        float mu = s*(1.f/D), rs = rsqrtf(sq*(1.f/D) - mu*mu + 1e-5f);
        s = 0.f; sq = 0.f;
        #pragma unroll
        for (int j = 0; j < 8; j++){
            int d = lane + j*64;
            float v = (e[j]-mu)*rs*g0[d] + b0[d] + ca[r*D + d];
            e[j] = v; s += v; sq += v*v;
        }
        s = wred(s); sq = wred(sq);
        mu = s*(1.f/D); rs = rsqrtf(sq*(1.f/D) - mu*mu + 1e-5f);
        #pragma unroll
        for (int j = 0; j < 8; j++){
            int d = lane + j*64;
            float z = (e[j]-mu)*rs*g1[d] + b1[d];
            if (xt && j >= jb && j < jb + 4) xt[(d - d0)*XP + rr] = z;
            if (zc && j == jc) zc[rr*64 + lane] = z;
        }
    }
}

// ---------------- per-step stages (device functions inside the persistent k) -

static __device__ void st_sa(float* smem, const float* wfold, const float* bfold,
                             const float* u3, fp lng, fp lnb, const int* tsrc,
                             fp emb, fp pe, float* u1, int l, int t, int bx)
{
    float* xt = smem;                       // 256*XP floats
    int cb = bx & 7, rbg = (bx >> 3) & 3, ks = bx >> 5;
    int tid = threadIdx.x;
    int r0 = rbg*16, d0 = ks*256;
    if (l == 0) pro_emb(xt, tsrc, emb, pe, t, r0, d0, tid);
    else        pro_ln4(xt, u3, lng + ((l-1)*3+2)*D, lnb + ((l-1)*3+2)*D, r0, d0, tid);
    __syncthreads();
    int lane = tid & 63, rb = tid >> 6;
    int c = cb*64 + lane;
    const float* W = wfold + (size_t)l*D*D + (size_t)d0*D + c;
    float bias = (ks == 0) ? bfold[l*D + c] : 0.f;
    float a0=bias, a1=bias, a2=bias, a3=bias;
    const float* xc = xt + rb*4;
    #pragma unroll 8
    for (int k = 0; k < 256; k++){
        float w = W[(size_t)k*D];
        float4 xv = *(const float4*)(xc + k*XP);
        a0 = fmaf(xv.x, w, a0); a1 = fmaf(xv.y, w, a1);
        a2 = fmaf(xv.z, w, a2); a3 = fmaf(xv.w, w, a3);
    }
    int r = r0 + rb*4;
    float* o = u1 + ks*B*D;
    o[(r+0)*D + c] = a0; o[(r+1)*D + c] = a1;
    o[(r+2)*D + c] = a2; o[(r+3)*D + c] = a3;
}

static __device__ void st_ffn1(float* smem, const float* u1, const float* ca,
                               fp lng, fp lnb, fp w1, fp b1, float* h, int l, int bx)
{
    float* zt = smem;                       // 256*XP floats
    int cb = bx & 31, rbg = (bx >> 5) & 3, ks = bx >> 7;
    int tid = threadIdx.x;
    int r0 = rbg*16, d0 = ks*256;
    pro_ln2(zt, nullptr, u1, ca + l*B*D,
            lng + l*3*D, lnb + l*3*D, lng + (l*3+1)*D, lnb + (l*3+1)*D,
            r0, d0, 0, tid);
    __syncthreads();
    int lane = tid & 63, rb = tid >> 6;
    int c = cb*64 + lane;
    const float* W = w1 + (size_t)l*D*F + (size_t)d0*F + c;
    float bias = (ks == 0) ? b1[l*F + c] : 0.f;
    float a0=bias, a1=bias, a2=bias, a3=bias;
    const float* xc = zt + rb*4;
    #pragma unroll 8
    for (int k = 0; k < 256; k++){
        float w = W[(size_t)k*F];
        float4 xv = *(const float4*)(xc + k*XP);
        a0 = fmaf(xv.x, w, a0); a1 = fmaf(xv.y, w, a1);
        a2 = fmaf(xv.z, w, a2); a3 = fmaf(xv.w, w, a3);
    }
    int r = r0 + rb*4;
    float* o = h + ks*B*F;
    o[(r+0)*F + c] = a0; o[(r+1)*F + c] = a1;
    o[(r+2)*F + c] = a2; o[(r+3)*F + c] = a3;
}

static __device__ void st_ffn2(float* smem, const float* u1, const float* ca,
                               fp lng, fp lnb, const float* h, fp w2, fp b2,
                               float* u3, int l, int bx)
{
    float* ht = smem;                       // 512*XP floats
    float* zc = smem + 512*XP;              // 16*64 floats
    int cb = bx & 7, rbg = (bx >> 3) & 3, kh = bx >> 5;
    int tid = threadIdx.x;
    int r0 = rbg*16, c0 = cb*64;
    if (kh == 0)
        pro_ln2(nullptr, zc, u1, ca + l*B*D,
                lng + l*3*D, lnb + l*3*D, lng + (l*3+1)*D, lnb + (l*3+1)*D,
                r0, 0, c0, tid);
    for (int i = tid; i < 16*512; i += 256){
        int rr = i >> 9, kk = i & 511;
        int gi = (r0+rr)*F + kh*512 + kk;
        ht[kk*XP + rr] = fmaxf(h[gi] + h[B*F + gi], 0.f);
    }
    __syncthreads();
    int lane = tid & 63, rb = tid >> 6;
    int c = c0 + lane;
    const float* W = w2 + (size_t)l*F*D + (size_t)kh*512*D + c;
    float a0, a1, a2, a3;
    if (kh == 0){
        float bb = b2[l*D + c];
        a0 = bb + zc[(rb*4+0)*64 + lane];
        a1 = bb + zc[(rb*4+1)*64 + lane];
        a2 = bb + zc[(rb*4+2)*64 + lane];
        a3 = bb + zc[(rb*4+3)*64 + lane];
    } else { a0=a1=a2=a3=0.f; }
    const float* xc = ht + rb*4;
    #pragma unroll 8
    for (int k = 0; k < 512; k++){
        float w = W[(size_t)k*D];
        float4 xv = *(const float4*)(xc + k*XP);
        a0 = fmaf(xv.x, w, a0); a1 = fmaf(xv.y, w, a1);
        a2 = fmaf(xv.z, w, a2); a3 = fmaf(xv.w, w, a3);
    }
    int r = r0 + rb*4;
    float* o = u3 + kh*B*D;
    o[(r+0)*D + c] = a0; o[(r+1)*D + c] = a1;
    o[(r+2)*D + c] = a2; o[(r+3)*D + c] = a3;
}

static __device__ void st_logits(float* smem, const float* u3, fp lng, fp lnb,
                                 fp outw, fp outb, float* lgt, int bx)
{
    float* xt = smem;                       // 256*XP floats
    int cb = bx & 63, rbg = (bx >> 6) & 3, ks = bx >> 8;
    int tid = threadIdx.x;
    int r0 = rbg*16, d0 = ks*256;
    pro_ln4(xt, u3, lng + 11*D, lnb + 11*D, r0, d0, tid);
    __syncthreads();
    int lane = tid & 63, rb = tid >> 6;
    int c = cb*64 + lane;
    const float* W = outw + (size_t)d0*V + c;
    float bias = (ks == 0) ? outb[c] : 0.f;
    float a0=bias, a1=bias, a2=bias, a3=bias;
    const float* xc = xt + rb*4;
    #pragma unroll 8
    for (int k = 0; k < 256; k++){
        float w = W[(size_t)k*V];
        float4 xv = *(const float4*)(xc + k*XP);
        a0 = fmaf(xv.x, w, a0); a1 = fmaf(xv.y, w, a1);
        a2 = fmaf(xv.z, w, a2); a3 = fmaf(xv.w, w, a3);
    }
    int r = r0 + rb*4;
    float* o = lgt + ks*B*V;
    o[(r+0)*V + c] = a0; o[(r+1)*V + c] = a1;
    o[(r+2)*V + c] = a2; o[(r+3)*V + c] = a3;
}

static __device__ void st_final(float* smem, const float* lgt, float* out,
                                int* tok, int t, int bx)
{
    float* sm = smem;                       // 4 floats
    float* ss = smem + 4;                   // 4 floats
    int*   si = (int*)(smem + 8);           // 4 ints
    int b = bx, tid = threadIdx.x;
    int lane = tid & 63, wid = tid >> 6;
    const float* l0 = lgt + b*V;
    const float* l1 = lgt + B*V + b*V;
    float m = -3.4e38f; int mi = 0;
    for (int i = tid; i < V; i += 256){
        float v = l0[i] + l1[i];
        if (v > m){ m = v; mi = i; }
    }
    #pragma unroll
    for (int o = 32; o > 0; o >>= 1){
        float om = __shfl_xor(m, o, 64);
        int   oi = __shfl_xor(mi, o, 64);
        if (om > m || (om == m && oi < mi)){ m = om; mi = oi; }
    }
    if (lane == 0){ sm[wid] = m; si[wid] = mi; }
    __syncthreads();
    if (tid == 0){
        #pragma unroll
        for (int w = 1; w < 4; w++)
            if (sm[w] > sm[0] || (sm[w] == sm[0] && si[w] < si[0])){ sm[0]=sm[w]; si[0]=si[w]; }
        tok[b] = si[0];
    }
    __syncthreads();
    m = sm[0];
    float s = 0.f;
    for (int i = tid; i < V; i += 256) s += expf(l0[i] + l1[i] - m);
    s = wred(s);
    if (lane == 0) ss[wid] = s;
    __syncthreads();
    float inv = 1.f / (ss[0] + ss[1] + ss[2] + ss[3]);
    float* orow = out + ((size_t)b*T + t)*V;
    for (int i = tid; i < V; i += 256)
        orow[i] = expf(l0[i] + l1[i] - m) * inv;
}

// ---------------- the persistent decode kernel -------------------------------
__global__ __launch_bounds__(256, 2) void k_decode(
    const float* wfold, const float* bfold, const float* ca_o,
    fp lng, fp lnb, const int* itok, fp emb, fp pe,
    fp w1, fp b1, fp w2, fp b2, fp outw, fp outb,
    float* u1, float* hbuf, float* u3, float* lgt,
    int* tok, unsigned* bar, float* out)
{
    __shared__ float smem[512*XP + 16*64];  // 11264 floats = 45 KB (ffn2 is max)
    int bx = blockIdx.x;
    unsigned ph = 0;
    for (int t = 0; t < T; t++){
        const int* tsrc = (t == 0) ? itok : tok;
        for (int l = 0; l < 4; l++){
            if (bx < 64)
                st_sa(smem, wfold, bfold, u3, lng, lnb, tsrc, emb, pe, u1, l, t, bx);
            ph++; gsync(bar, ph);
            if (bx < 256)
                st_ffn1(smem, u1, ca_o, lng, lnb, w1, b1, hbuf, l, bx);
            ph++; gsync(bar, ph);
            if (bx < 128)
                st_ffn2(smem, u1, ca_o, lng, lnb, hbuf, w2, b2, u3, l, bx);
            ph++; gsync(bar, ph);
        }
        st_logits(smem, u3, lng, lnb, outw, outb, lgt, bx);   // all 512 wgs
        ph++; gsync(bar, ph);
        if (bx < 64)
            st_final(smem, lgt, out, tok, t, bx);
        ph++; gsync(bar, ph);
    }
}

// ---------------------------------------------------------------------------
extern "C" void kernel_launch(void* const* d_in, const int* in_sizes, int n_in,
                              void* d_out, int out_size, void* d_ws, size_t ws_size,
                              hipStream_t stream)
{
    fp prot = (fp)d_in[0];
    const int* itok = (const int*)d_in[1];
    fp p1w=(fp)d_in[2], p1b=(fp)d_in[3], p2w=(fp)d_in[4], p2b=(fp)d_in[5];
    fp emb=(fp)d_in[6], saw=(fp)d_in[7], sab=(fp)d_in[8];
    fp caw=(fp)d_in[9], cab=(fp)d_in[10];
    fp w1=(fp)d_in[11], b1=(fp)d_in[12], w2=(fp)d_in[13], b2=(fp)d_in[14];
    fp lng=(fp)d_in[15], lnb=(fp)d_in[16];
    fp outw=(fp)d_in[17], outb=(fp)d_in[18], pe=(fp)d_in[19];

    char* w = (char*)d_ws;
    float* wfold = (float*)w;  w += (size_t)4*D*D*4;   // 4 MB
    float* bfold = (float*)w;  w += 4*D*4;
    float* ca_o  = (float*)w;  w += 4*B*D*4;
    float* u1    = (float*)w;  w += 2*B*D*4;           // 2 K-partials
    float* hbuf  = (float*)w;  w += 2*B*F*4;           // 2 K-partials
    float* u3    = (float*)w;  w += 4*B*D*4;           // 4 K-partials
    float* lgt   = (float*)w;  w += 2*B*V*4;           // 2 K-partials
    int*   tok   = (int*)w;    w += 256;
    unsigned* bar = (unsigned*)w; w += 2048*4;         // 64 slots x 128B

    float* out = (float*)d_out;

    k_setup_mem<<<64, 256, 0, stream>>>(prot, p1w, p1b, p2w, p2b, caw, cab, ca_o);
    k_fold_sa<<<256, 256, 0, stream>>>(saw, sab, wfold, bfold);
    k_init<<<8, 256, 0, stream>>>(bar);                // zero barrier slots (every replay)

    k_decode<<<NWG, 256, 0, stream>>>(
        wfold, bfold, ca_o, lng, lnb, itok, emb, pe,
        w1, b1, w2, b2, outw, outb,
        u1, hbuf, u3, lgt, tok, bar, out);
}

// Round 2
// 143429.431 us; speedup vs baseline: 1.2700x; 1.2700x over previous
//
#include <hip/hip_runtime.h>

// DNADecoder: B=64,T=128,P=1024,D=512,F=2048,V=4096,L=4
// Persistent-kernel decode (512 wgs x 256 thr, co-resident: LDS 45KB -> 3 wg/CU
// capacity, VGPR<=128 -> 8 waves/CU; grid 512 = 2 wg/CU).
// Grid sync is FENCE-FREE: cross-wg activations (u1,h,u3,lgt,tok) use
// agent-scope relaxed atomics (coherent at MALL, no L2 flush); weights stay
// plain cached loads and remain L2/L3-resident. __syncthreads()'s implicit
// vmcnt(0) drain orders stores before the arrival fetch_add.

#define B 64
#define T 128
#define PP 1024
#define D 512
#define F 2048
#define V 4096
#define XP 20       // padded row-stride (floats) for transposed LDS tiles
#define NWG 512     // persistent grid size (2 wgs per CU on 256 CUs)

typedef const float* fp;

static __device__ __forceinline__ float wred(float s){
    #pragma unroll
    for (int o = 32; o > 0; o >>= 1) s += __shfl_xor(s, o, 64);
    return s;
}

// agent-coherent scalar accessors (bypass non-coherent L2, no fences needed)
static __device__ __forceinline__ float gload(const float* p){
    return __hip_atomic_load(p, __ATOMIC_RELAXED, __HIP_MEMORY_SCOPE_AGENT);
}
static __device__ __forceinline__ void gstore(float* p, float v){
    __hip_atomic_store(p, v, __ATOMIC_RELAXED, __HIP_MEMORY_SCOPE_AGENT);
}
static __device__ __forceinline__ int gloadi(const int* p){
    return __hip_atomic_load(p, __ATOMIC_RELAXED, __HIP_MEMORY_SCOPE_AGENT);
}
static __device__ __forceinline__ void gstorei(int* p, int v){
    __hip_atomic_store(p, v, __ATOMIC_RELAXED, __HIP_MEMORY_SCOPE_AGENT);
}

// ---------------- grid barrier: 64 slots, 128B apart; monotonic counters ----
// NO cache-flushing fences. All cross-wg data moves via agent-scope atomics.
static __device__ __forceinline__ void gsync(unsigned* bar, unsigned ph){
    __syncthreads();   // compiler drains vmcnt(0) per wave before s_barrier
    int tid = threadIdx.x;
    if (tid == 0)
        __hip_atomic_fetch_add(&bar[(blockIdx.x & 63) << 5], 1u,
                               __ATOMIC_RELAXED, __HIP_MEMORY_SCOPE_AGENT);
    if (tid < 64){
        unsigned tgt = ph * (unsigned)NWG;
        for (;;){
            unsigned v = __hip_atomic_load(&bar[tid << 5],
                                           __ATOMIC_RELAXED, __HIP_MEMORY_SCOPE_AGENT);
            #pragma unroll
            for (int o = 32; o > 0; o >>= 1) v += __shfl_xor(v, o, 64);
            if (v >= tgt) break;
            __builtin_amdgcn_s_sleep(8);
        }
    }
    __syncthreads();
}

__global__ void k_init(unsigned* bar){
    bar[blockIdx.x * 256 + threadIdx.x] = 0u;
}

// ---------------- setup: protein -> mem1 -> per-layer cross-attn constant ----
__global__ __launch_bounds__(256) void k_setup_mem(
    fp prot, fp p1w, fp p1b, fp p2w, fp p2b,
    fp caw, fp cab, float* ca_out)
{
    __shared__ float xp[PP];
    __shared__ float hr[PP];
    __shared__ float m1[D];
    __shared__ float tv[D];
    int b = blockIdx.x, tid = threadIdx.x;
    for (int i = tid; i < PP; i += 256) xp[i] = prot[b*PP + i];
    __syncthreads();
    for (int c = tid; c < 1024; c += 256){
        float acc = p1b[c];
        for (int k = 0; k < PP; k++) acc = fmaf(xp[k], p1w[k*1024 + c], acc);
        hr[c] = fmaxf(acc, 0.f);
    }
    __syncthreads();
    for (int c = tid; c < D; c += 256){
        float acc = p2b[c];
        for (int k = 0; k < 1024; k++) acc = fmaf(hr[k], p2w[k*D + c], acc);
        m1[c] = acc;
    }
    __syncthreads();
    for (int l = 0; l < 4; l++){
        const float* wv = caw + (size_t)(l*4 + 2)*D*D;
        const float* bv = cab + (l*4 + 2)*D;
        for (int c = tid; c < D; c += 256){
            float acc = bv[c];
            for (int k = 0; k < D; k++) acc = fmaf(m1[k], wv[k*D + c], acc);
            tv[c] = acc;
        }
        __syncthreads();
        const float* wo = caw + (size_t)(l*4 + 3)*D*D;
        const float* bo = cab + (l*4 + 3)*D;
        for (int c = tid; c < D; c += 256){
            float acc = bo[c];
            for (int k = 0; k < D; k++) acc = fmaf(tv[k], wo[k*D + c], acc);
            ca_out[(l*B + b)*D + c] = acc;
        }
        __syncthreads();
    }
}

// ---------------- setup: fold self-attn  Wfold = Wv@Wo + I, bfold = bv@Wo+bo --
__global__ __launch_bounds__(256) void k_fold_sa(
    fp saw, fp sab, float* wfold, float* bfold)
{
    int l = blockIdx.x >> 6;
    int kb = blockIdx.x & 63;              // 8 rows of Wfold each
    int tid = threadIdx.x;
    const float* Wv = saw + (size_t)(l*4 + 2)*D*D;
    const float* Wo = saw + (size_t)(l*4 + 3)*D*D;
    __shared__ float a[8][D];
    for (int i = tid; i < 8*D; i += 256){
        int r = i >> 9, m = i & 511;
        a[r][m] = Wv[(kb*8 + r)*D + m];
    }
    __syncthreads();
    for (int cc = 0; cc < 2; cc++){
        int c = tid + cc*256;
        float acc[8];
        #pragma unroll
        for (int r = 0; r < 8; r++) acc[r] = 0.f;
        for (int m = 0; m < D; m++){
            float w = Wo[m*D + c];
            #pragma unroll
            for (int r = 0; r < 8; r++) acc[r] = fmaf(a[r][m], w, acc[r]);
        }
        #pragma unroll
        for (int r = 0; r < 8; r++){
            int kg = kb*8 + r;
            wfold[((size_t)l*D + kg)*D + c] = acc[r] + (kg == c ? 1.f : 0.f);
        }
    }
    if (kb == 0){
        const float* bv = sab + (l*4 + 2)*D;
        const float* bo = sab + (l*4 + 3)*D;
        for (int c = tid; c < D; c += 256){
            float acc = bo[c];
            for (int m = 0; m < D; m++) acc = fmaf(bv[m], Wo[m*D + c], acc);
            bfold[l*D + c] = acc;
        }
    }
}

// ---------- prologues: build transposed padded LDS x^T tile for 16 rows -------
static __device__ void pro_emb(float* xt, const int* tok, fp emb, fp pe,
                               int t, int r0, int d0, int tid)
{
    int lane = tid & 63, wid = tid >> 6;
    for (int i = 0; i < 4; i++){
        int rr = wid*4 + i;
        int tk = gloadi(tok + r0 + rr);
        const float* er = emb + (size_t)tk*D + d0;
        const float* pr = pe + t*D + d0;
        #pragma unroll
        for (int j = 0; j < 4; j++){
            int d = lane + j*64;
            xt[d*XP + rr] = er[d] + pr[d];
        }
    }
}

static __device__ void pro_ln4(float* xt, const float* u3, fp g, fp bb,
                               int r0, int d0, int tid)
{
    int lane = tid & 63, wid = tid >> 6;
    int jb = d0 >> 6;
    for (int i = 0; i < 4; i++){
        int rr = wid*4 + i, r = r0 + rr;
        float e[8]; float s = 0.f, sq = 0.f;
        #pragma unroll
        for (int j = 0; j < 8; j++){
            int d = lane + j*64;
            float v = gload(u3 + r*D + d) + gload(u3 + B*D + r*D + d)
                    + gload(u3 + 2*B*D + r*D + d) + gload(u3 + 3*B*D + r*D + d);
            e[j] = v; s += v; sq += v*v;
        }
        s = wred(s); sq = wred(sq);
        float mu = s*(1.f/D);
        float rs = rsqrtf(sq*(1.f/D) - mu*mu + 1e-5f);
        #pragma unroll
        for (int j = 0; j < 8; j++){
            int d = lane + j*64;
            if (j >= jb && j < jb + 4)
                xt[(d - d0)*XP + rr] = (e[j]-mu)*rs*g[d] + bb[d];
        }
    }
}

static __device__ void pro_ln2(float* xt, float* zc, const float* u1, const float* ca,
                               fp g0, fp b0, fp g1, fp b1,
                               int r0, int d0, int c0, int tid)
{
    int lane = tid & 63, wid = tid >> 6;
    int jb = d0 >> 6, jc = c0 >> 6;
    for (int i = 0; i < 4; i++){
        int rr = wid*4 + i, r = r0 + rr;
        float e[8]; float s = 0.f, sq = 0.f;
        #pragma unroll
        for (int j = 0; j < 8; j++){
            int d = lane + j*64;
            float v = gload(u1 + r*D + d) + gload(u1 + B*D + r*D + d);
            e[j] = v; s += v; sq += v*v;
        }
        s = wred(s); sq = wred(sq);
        float mu = s*(1.f/D), rs = rsqrtf(sq*(1.f/D) - mu*mu + 1e-5f);
        s = 0.f; sq = 0.f;
        #pragma unroll
        for (int j = 0; j < 8; j++){
            int d = lane + j*64;
            float v = (e[j]-mu)*rs*g0[d] + b0[d] + ca[r*D + d];
            e[j] = v; s += v; sq += v*v;
        }
        s = wred(s); sq = wred(sq);
        mu = s*(1.f/D); rs = rsqrtf(sq*(1.f/D) - mu*mu + 1e-5f);
        #pragma unroll
        for (int j = 0; j < 8; j++){
            int d = lane + j*64;
            float z = (e[j]-mu)*rs*g1[d] + b1[d];
            if (xt && j >= jb && j < jb + 4) xt[(d - d0)*XP + rr] = z;
            if (zc && j == jc) zc[rr*64 + lane] = z;
        }
    }
}

// ---------------- per-step stages (device functions inside the persistent k) -

static __device__ void st_sa(float* smem, const float* wfold, const float* bfold,
                             const float* u3, fp lng, fp lnb, const int* tsrc,
                             fp emb, fp pe, float* u1, int l, int t, int bx)
{
    float* xt = smem;                       // 256*XP floats
    int cb = bx & 7, rbg = (bx >> 3) & 3, ks = bx >> 5;
    int tid = threadIdx.x;
    int r0 = rbg*16, d0 = ks*256;
    if (l == 0) pro_emb(xt, tsrc, emb, pe, t, r0, d0, tid);
    else        pro_ln4(xt, u3, lng + ((l-1)*3+2)*D, lnb + ((l-1)*3+2)*D, r0, d0, tid);
    __syncthreads();
    int lane = tid & 63, rb = tid >> 6;
    int c = cb*64 + lane;
    const float* W = wfold + (size_t)l*D*D + (size_t)d0*D + c;
    float bias = (ks == 0) ? bfold[l*D + c] : 0.f;
    float a0=bias, a1=bias, a2=bias, a3=bias;
    const float* xc = xt + rb*4;
    #pragma unroll 8
    for (int k = 0; k < 256; k++){
        float w = W[(size_t)k*D];
        float4 xv = *(const float4*)(xc + k*XP);
        a0 = fmaf(xv.x, w, a0); a1 = fmaf(xv.y, w, a1);
        a2 = fmaf(xv.z, w, a2); a3 = fmaf(xv.w, w, a3);
    }
    int r = r0 + rb*4;
    float* o = u1 + ks*B*D;
    gstore(o + (r+0)*D + c, a0); gstore(o + (r+1)*D + c, a1);
    gstore(o + (r+2)*D + c, a2); gstore(o + (r+3)*D + c, a3);
}

static __device__ void st_ffn1(float* smem, const float* u1, const float* ca,
                               fp lng, fp lnb, fp w1, fp b1, float* h, int l, int bx)
{
    float* zt = smem;                       // 256*XP floats
    int cb = bx & 31, rbg = (bx >> 5) & 3, ks = bx >> 7;
    int tid = threadIdx.x;
    int r0 = rbg*16, d0 = ks*256;
    pro_ln2(zt, nullptr, u1, ca + l*B*D,
            lng + l*3*D, lnb + l*3*D, lng + (l*3+1)*D, lnb + (l*3+1)*D,
            r0, d0, 0, tid);
    __syncthreads();
    int lane = tid & 63, rb = tid >> 6;
    int c = cb*64 + lane;
    const float* W = w1 + (size_t)l*D*F + (size_t)d0*F + c;
    float bias = (ks == 0) ? b1[l*F + c] : 0.f;
    float a0=bias, a1=bias, a2=bias, a3=bias;
    const float* xc = zt + rb*4;
    #pragma unroll 8
    for (int k = 0; k < 256; k++){
        float w = W[(size_t)k*F];
        float4 xv = *(const float4*)(xc + k*XP);
        a0 = fmaf(xv.x, w, a0); a1 = fmaf(xv.y, w, a1);
        a2 = fmaf(xv.z, w, a2); a3 = fmaf(xv.w, w, a3);
    }
    int r = r0 + rb*4;
    float* o = h + ks*B*F;
    gstore(o + (r+0)*F + c, a0); gstore(o + (r+1)*F + c, a1);
    gstore(o + (r+2)*F + c, a2); gstore(o + (r+3)*F + c, a3);
}

static __device__ void st_ffn2(float* smem, const float* u1, const float* ca,
                               fp lng, fp lnb, const float* h, fp w2, fp b2,
                               float* u3, int l, int bx)
{
    float* ht = smem;                       // 512*XP floats
    float* zc = smem + 512*XP;              // 16*64 floats
    int cb = bx & 7, rbg = (bx >> 3) & 3, kh = bx >> 5;
    int tid = threadIdx.x;
    int r0 = rbg*16, c0 = cb*64;
    if (kh == 0)
        pro_ln2(nullptr, zc, u1, ca + l*B*D,
                lng + l*3*D, lnb + l*3*D, lng + (l*3+1)*D, lnb + (l*3+1)*D,
                r0, 0, c0, tid);
    for (int i = tid; i < 16*512; i += 256){
        int rr = i >> 9, kk = i & 511;
        int gi = (r0+rr)*F + kh*512 + kk;
        ht[kk*XP + rr] = fmaxf(gload(h + gi) + gload(h + B*F + gi), 0.f);
    }
    __syncthreads();
    int lane = tid & 63, rb = tid >> 6;
    int c = c0 + lane;
    const float* W = w2 + (size_t)l*F*D + (size_t)kh*512*D + c;
    float a0, a1, a2, a3;
    if (kh == 0){
        float bb = b2[l*D + c];
        a0 = bb + zc[(rb*4+0)*64 + lane];
        a1 = bb + zc[(rb*4+1)*64 + lane];
        a2 = bb + zc[(rb*4+2)*64 + lane];
        a3 = bb + zc[(rb*4+3)*64 + lane];
    } else { a0=a1=a2=a3=0.f; }
    const float* xc = ht + rb*4;
    #pragma unroll 8
    for (int k = 0; k < 512; k++){
        float w = W[(size_t)k*D];
        float4 xv = *(const float4*)(xc + k*XP);
        a0 = fmaf(xv.x, w, a0); a1 = fmaf(xv.y, w, a1);
        a2 = fmaf(xv.z, w, a2); a3 = fmaf(xv.w, w, a3);
    }
    int r = r0 + rb*4;
    float* o = u3 + kh*B*D;
    gstore(o + (r+0)*D + c, a0); gstore(o + (r+1)*D + c, a1);
    gstore(o + (r+2)*D + c, a2); gstore(o + (r+3)*D + c, a3);
}

static __device__ void st_logits(float* smem, const float* u3, fp lng, fp lnb,
                                 fp outw, fp outb, float* lgt, int bx)
{
    float* xt = smem;                       // 256*XP floats
    int cb = bx & 63, rbg = (bx >> 6) & 3, ks = bx >> 8;
    int tid = threadIdx.x;
    int r0 = rbg*16, d0 = ks*256;
    pro_ln4(xt, u3, lng + 11*D, lnb + 11*D, r0, d0, tid);
    __syncthreads();
    int lane = tid & 63, rb = tid >> 6;
    int c = cb*64 + lane;
    const float* W = outw + (size_t)d0*V + c;
    float bias = (ks == 0) ? outb[c] : 0.f;
    float a0=bias, a1=bias, a2=bias, a3=bias;
    const float* xc = xt + rb*4;
    #pragma unroll 8
    for (int k = 0; k < 256; k++){
        float w = W[(size_t)k*V];
        float4 xv = *(const float4*)(xc + k*XP);
        a0 = fmaf(xv.x, w, a0); a1 = fmaf(xv.y, w, a1);
        a2 = fmaf(xv.z, w, a2); a3 = fmaf(xv.w, w, a3);
    }
    int r = r0 + rb*4;
    float* o = lgt + ks*B*V;
    gstore(o + (r+0)*V + c, a0); gstore(o + (r+1)*V + c, a1);
    gstore(o + (r+2)*V + c, a2); gstore(o + (r+3)*V + c, a3);
}

static __device__ void st_final(float* smem, const float* lgt, float* out,
                                int* tok, int t, int bx)
{
    float* sm = smem;                       // 4 floats
    float* ss = smem + 4;                   // 4 floats
    int*   si = (int*)(smem + 8);           // 4 ints
    int b = bx, tid = threadIdx.x;
    int lane = tid & 63, wid = tid >> 6;
    const float* l0 = lgt + b*V;
    const float* l1 = lgt + B*V + b*V;
    float v[16];
    #pragma unroll
    for (int ii = 0; ii < 16; ii++){
        int i = tid + ii*256;
        v[ii] = gload(l0 + i) + gload(l1 + i);
    }
    float m = -3.4e38f; int mi = 0;
    #pragma unroll
    for (int ii = 0; ii < 16; ii++){
        int i = tid + ii*256;
        if (v[ii] > m){ m = v[ii]; mi = i; }
    }
    #pragma unroll
    for (int o = 32; o > 0; o >>= 1){
        float om = __shfl_xor(m, o, 64);
        int   oi = __shfl_xor(mi, o, 64);
        if (om > m || (om == m && oi < mi)){ m = om; mi = oi; }
    }
    if (lane == 0){ sm[wid] = m; si[wid] = mi; }
    __syncthreads();
    if (tid == 0){
        #pragma unroll
        for (int w = 1; w < 4; w++)
            if (sm[w] > sm[0] || (sm[w] == sm[0] && si[w] < si[0])){ sm[0]=sm[w]; si[0]=si[w]; }
        gstorei(tok + b, si[0]);
    }
    __syncthreads();
    m = sm[0];
    float s = 0.f;
    #pragma unroll
    for (int ii = 0; ii < 16; ii++) s += expf(v[ii] - m);
    s = wred(s);
    if (lane == 0) ss[wid] = s;
    __syncthreads();
    float inv = 1.f / (ss[0] + ss[1] + ss[2] + ss[3]);
    float* orow = out + ((size_t)b*T + t)*V;
    #pragma unroll
    for (int ii = 0; ii < 16; ii++){
        int i = tid + ii*256;
        orow[i] = expf(v[ii] - m) * inv;
    }
}

// ---------------- the persistent decode kernel -------------------------------
__global__ __launch_bounds__(256, 2) void k_decode(
    const float* wfold, const float* bfold, const float* ca_o,
    fp lng, fp lnb, const int* itok, fp emb, fp pe,
    fp w1, fp b1, fp w2, fp b2, fp outw, fp outb,
    float* u1, float* hbuf, float* u3, float* lgt,
    int* tok, unsigned* bar, float* out)
{
    __shared__ float smem[512*XP + 16*64];  // 11264 floats = 45 KB (ffn2 is max)
    int bx = blockIdx.x;
    unsigned ph = 0;
    for (int t = 0; t < T; t++){
        const int* tsrc = (t == 0) ? itok : tok;
        for (int l = 0; l < 4; l++){
            if (bx < 64)
                st_sa(smem, wfold, bfold, u3, lng, lnb, tsrc, emb, pe, u1, l, t, bx);
            ph++; gsync(bar, ph);
            if (bx < 256)
                st_ffn1(smem, u1, ca_o, lng, lnb, w1, b1, hbuf, l, bx);
            ph++; gsync(bar, ph);
            if (bx < 128)
                st_ffn2(smem, u1, ca_o, lng, lnb, hbuf, w2, b2, u3, l, bx);
            ph++; gsync(bar, ph);
        }
        st_logits(smem, u3, lng, lnb, outw, outb, lgt, bx);   // all 512 wgs
        ph++; gsync(bar, ph);
        if (bx < 64)
            st_final(smem, lgt, out, tok, t, bx);
        ph++; gsync(bar, ph);
    }
}

// ---------------------------------------------------------------------------
extern "C" void kernel_launch(void* const* d_in, const int* in_sizes, int n_in,
                              void* d_out, int out_size, void* d_ws, size_t ws_size,
                              hipStream_t stream)
{
    fp prot = (fp)d_in[0];
    const int* itok = (const int*)d_in[1];
    fp p1w=(fp)d_in[2], p1b=(fp)d_in[3], p2w=(fp)d_in[4], p2b=(fp)d_in[5];
    fp emb=(fp)d_in[6], saw=(fp)d_in[7], sab=(fp)d_in[8];
    fp caw=(fp)d_in[9], cab=(fp)d_in[10];
    fp w1=(fp)d_in[11], b1=(fp)d_in[12], w2=(fp)d_in[13], b2=(fp)d_in[14];
    fp lng=(fp)d_in[15], lnb=(fp)d_in[16];
    fp outw=(fp)d_in[17], outb=(fp)d_in[18], pe=(fp)d_in[19];

    char* w = (char*)d_ws;
    float* wfold = (float*)w;  w += (size_t)4*D*D*4;   // 4 MB
    float* bfold = (float*)w;  w += 4*D*4;
    float* ca_o  = (float*)w;  w += 4*B*D*4;
    float* u1    = (float*)w;  w += 2*B*D*4;           // 2 K-partials
    float* hbuf  = (float*)w;  w += 2*B*F*4;           // 2 K-partials
    float* u3    = (float*)w;  w += 4*B*D*4;           // 4 K-partials
    float* lgt   = (float*)w;  w += 2*B*V*4;           // 2 K-partials
    int*   tok   = (int*)w;    w += 256;
    unsigned* bar = (unsigned*)w; w += 2048*4;         // 64 slots x 128B

    float* out = (float*)d_out;

    k_setup_mem<<<64, 256, 0, stream>>>(prot, p1w, p1b, p2w, p2b, caw, cab, ca_o);
    k_fold_sa<<<256, 256, 0, stream>>>(saw, sab, wfold, bfold);
    k_init<<<8, 256, 0, stream>>>(bar);                // zero barrier slots (every replay)

    k_decode<<<NWG, 256, 0, stream>>>(
        wfold, bfold, ca_o, lng, lnb, itok, emb, pe,
        w1, b1, w2, b2, outw, outb,
        u1, hbuf, u3, lgt, tok, bar, out);
}

// Round 3
// 85219.745 us; speedup vs baseline: 2.1376x; 1.6831x over previous
//
#include <hip/hip_runtime.h>

// DNADecoder: B=64,T=128,P=1024,D=512,F=2048,V=4096,L=4
// Key insight: the decode is embarrassingly parallel across the B=64 batch
// rows (tok[b] feeds only row b). One 1024-thread workgroup per row runs all
// 128 steps with activations in LDS -- ZERO grid syncs, zero uncached traffic.
// Weights stream through L2/MALL as plain cached loads.

#define B 64
#define T 128
#define PP 1024
#define D 512
#define F 2048
#define V 4096

typedef const float* fp;

static __device__ __forceinline__ float wred(float s){
    #pragma unroll
    for (int o = 32; o > 0; o >>= 1) s += __shfl_xor(s, o, 64);
    return s;
}

// ---------------- setup: protein -> mem1 -> per-layer cross-attn constant ----
__global__ __launch_bounds__(256) void k_setup_mem(
    fp prot, fp p1w, fp p1b, fp p2w, fp p2b,
    fp caw, fp cab, float* ca_out)
{
    __shared__ float xp[PP];
    __shared__ float hr[PP];
    __shared__ float m1[D];
    __shared__ float tv[D];
    int b = blockIdx.x, tid = threadIdx.x;
    for (int i = tid; i < PP; i += 256) xp[i] = prot[b*PP + i];
    __syncthreads();
    for (int c = tid; c < 1024; c += 256){
        float acc = p1b[c];
        for (int k = 0; k < PP; k++) acc = fmaf(xp[k], p1w[k*1024 + c], acc);
        hr[c] = fmaxf(acc, 0.f);
    }
    __syncthreads();
    for (int c = tid; c < D; c += 256){
        float acc = p2b[c];
        for (int k = 0; k < 1024; k++) acc = fmaf(hr[k], p2w[k*D + c], acc);
        m1[c] = acc;
    }
    __syncthreads();
    for (int l = 0; l < 4; l++){
        const float* wv = caw + (size_t)(l*4 + 2)*D*D;
        const float* bv = cab + (l*4 + 2)*D;
        for (int c = tid; c < D; c += 256){
            float acc = bv[c];
            for (int k = 0; k < D; k++) acc = fmaf(m1[k], wv[k*D + c], acc);
            tv[c] = acc;
        }
        __syncthreads();
        const float* wo = caw + (size_t)(l*4 + 3)*D*D;
        const float* bo = cab + (l*4 + 3)*D;
        for (int c = tid; c < D; c += 256){
            float acc = bo[c];
            for (int k = 0; k < D; k++) acc = fmaf(tv[k], wo[k*D + c], acc);
            ca_out[(l*B + b)*D + c] = acc;
        }
        __syncthreads();
    }
}

// ---------------- setup: fold self-attn  Wfold = Wv@Wo + I, bfold = bv@Wo+bo --
__global__ __launch_bounds__(256) void k_fold_sa(
    fp saw, fp sab, float* wfold, float* bfold)
{
    int l = blockIdx.x >> 6;
    int kb = blockIdx.x & 63;              // 8 rows of Wfold each
    int tid = threadIdx.x;
    const float* Wv = saw + (size_t)(l*4 + 2)*D*D;
    const float* Wo = saw + (size_t)(l*4 + 3)*D*D;
    __shared__ float a[8][D];
    for (int i = tid; i < 8*D; i += 256){
        int r = i >> 9, m = i & 511;
        a[r][m] = Wv[(kb*8 + r)*D + m];
    }
    __syncthreads();
    for (int cc = 0; cc < 2; cc++){
        int c = tid + cc*256;
        float acc[8];
        #pragma unroll
        for (int r = 0; r < 8; r++) acc[r] = 0.f;
        for (int m = 0; m < D; m++){
            float w = Wo[m*D + c];
            #pragma unroll
            for (int r = 0; r < 8; r++) acc[r] = fmaf(a[r][m], w, acc[r]);
        }
        #pragma unroll
        for (int r = 0; r < 8; r++){
            int kg = kb*8 + r;
            wfold[((size_t)l*D + kg)*D + c] = acc[r] + (kg == c ? 1.f : 0.f);
        }
    }
    if (kb == 0){
        const float* bv = sab + (l*4 + 2)*D;
        const float* bo = sab + (l*4 + 3)*D;
        for (int c = tid; c < D; c += 256){
            float acc = bo[c];
            for (int m = 0; m < D; m++) acc = fmaf(bv[m], Wo[m*D + c], acc);
            bfold[l*D + c] = acc;
        }
    }
}

// ---------------- the per-row full-decode kernel -----------------------------
// 64 wgs x 1024 thr. Row b = blockIdx.x. All activations in LDS.
// GEMV pattern: thread covers a float2 column pair; k split across 4 groups
// (h = tid>>8) with LDS partial reduce; x[k] reads are LDS broadcasts.
__global__ __launch_bounds__(1024) void k_row_decode(
    const float* wfold, const float* bfold, const float* ca_o,
    fp lng, fp lnb, const int* itok, fp emb, fp pe,
    fp w1, fp b1, fp w2, fp b2, fp outw, fp outb, float* out)
{
    __shared__ float xv[D];        // layer input / LN2 output
    __shared__ float zv[D];        // post-LN1 (ffn input, residual)
    __shared__ float hb[F];        // relu(ffn1)
    __shared__ float pr[2048];     // k-split partials (4 x 512)
    __shared__ float red[64];      // wave-reduction scratch
    __shared__ int  redI[16];

    const int b = blockIdx.x;
    const int tid = threadIdx.x;
    const int lane = tid & 63, wave = tid >> 6;
    const int p = tid & 255, h = tid >> 8;    // col-pair id, k-chunk id
    int tok = itok[b];

    for (int t = 0; t < T; t++){
        // x = emb[tok] + pe[t]
        if (tid < D) xv[tid] = emb[(size_t)tok*D + tid] + pe[t*D + tid];
        __syncthreads();

        for (int l = 0; l < 4; l++){
            // ---- u1 = x @ Wfold[l] (+bias at combine); k-split 4x128 --------
            {
                const float* W = wfold + (size_t)l*D*D + (size_t)(h*128)*D + 2*p;
                const float* xk = xv + h*128;
                float2 acc = make_float2(0.f, 0.f);
                #pragma unroll 2
                for (int k = 0; k < 128; k += 4){
                    float4 x4 = *(const float4*)(xk + k);
                    float2 w0 = *(const float2*)(W + (size_t)(k+0)*D);
                    float2 wA = *(const float2*)(W + (size_t)(k+1)*D);
                    float2 wB = *(const float2*)(W + (size_t)(k+2)*D);
                    float2 wC = *(const float2*)(W + (size_t)(k+3)*D);
                    acc.x = fmaf(x4.x, w0.x, acc.x); acc.y = fmaf(x4.x, w0.y, acc.y);
                    acc.x = fmaf(x4.y, wA.x, acc.x); acc.y = fmaf(x4.y, wA.y, acc.y);
                    acc.x = fmaf(x4.z, wB.x, acc.x); acc.y = fmaf(x4.z, wB.y, acc.y);
                    acc.x = fmaf(x4.w, wC.x, acc.x); acc.y = fmaf(x4.w, wC.y, acc.y);
                }
                *(float2*)(pr + h*512 + 2*p) = acc;
            }
            __syncthreads();
            // ---- combine + LN0 + ca + LN1 -> zv -----------------------------
            {
                float u1 = 0.f;
                if (tid < D)
                    u1 = pr[tid] + pr[512+tid] + pr[1024+tid] + pr[1536+tid]
                       + bfold[l*D + tid];
                float s  = wred(tid < D ? u1 : 0.f);
                float sq = wred(tid < D ? u1*u1 : 0.f);
                if (lane == 0){ red[wave] = s; red[16+wave] = sq; }
                __syncthreads();
                s = 0.f; sq = 0.f;
                #pragma unroll
                for (int w = 0; w < 16; w++){ s += red[w]; sq += red[16+w]; }
                float mu = s*(1.f/D), rs = rsqrtf(sq*(1.f/D) - mu*mu + 1e-5f);
                float z0 = 0.f;
                if (tid < D)
                    z0 = (u1 - mu)*rs*lng[(l*3)*D + tid] + lnb[(l*3)*D + tid]
                       + ca_o[((size_t)l*B + b)*D + tid];
                s  = wred(tid < D ? z0 : 0.f);
                sq = wred(tid < D ? z0*z0 : 0.f);
                if (lane == 0){ red[32+wave] = s; red[48+wave] = sq; }
                __syncthreads();
                s = 0.f; sq = 0.f;
                #pragma unroll
                for (int w = 0; w < 16; w++){ s += red[32+w]; sq += red[48+w]; }
                mu = s*(1.f/D); rs = rsqrtf(sq*(1.f/D) - mu*mu + 1e-5f);
                if (tid < D)
                    zv[tid] = (z0 - mu)*rs*lng[(l*3+1)*D + tid] + lnb[(l*3+1)*D + tid];
            }
            __syncthreads();
            // ---- hb = relu(zv @ W1 + b1); cols 2*tid, full K ----------------
            {
                const float* W = w1 + (size_t)l*D*F + 2*tid;
                float2 acc = *(const float2*)(b1 + l*F + 2*tid);
                #pragma unroll 2
                for (int k = 0; k < D; k += 4){
                    float4 x4 = *(const float4*)(zv + k);
                    float2 w0 = *(const float2*)(W + (size_t)(k+0)*F);
                    float2 wA = *(const float2*)(W + (size_t)(k+1)*F);
                    float2 wB = *(const float2*)(W + (size_t)(k+2)*F);
                    float2 wC = *(const float2*)(W + (size_t)(k+3)*F);
                    acc.x = fmaf(x4.x, w0.x, acc.x); acc.y = fmaf(x4.x, w0.y, acc.y);
                    acc.x = fmaf(x4.y, wA.x, acc.x); acc.y = fmaf(x4.y, wA.y, acc.y);
                    acc.x = fmaf(x4.z, wB.x, acc.x); acc.y = fmaf(x4.z, wB.y, acc.y);
                    acc.x = fmaf(x4.w, wC.x, acc.x); acc.y = fmaf(x4.w, wC.y, acc.y);
                }
                *(float2*)(hb + 2*tid) = make_float2(fmaxf(acc.x, 0.f), fmaxf(acc.y, 0.f));
            }
            __syncthreads();
            // ---- u3 partials = hb @ W2; k-split 4x512 -----------------------
            {
                const float* W = w2 + (size_t)l*F*D + (size_t)(h*512)*D + 2*p;
                const float* hk = hb + h*512;
                float2 acc = make_float2(0.f, 0.f);
                #pragma unroll 2
                for (int k = 0; k < 512; k += 4){
                    float4 x4 = *(const float4*)(hk + k);
                    float2 w0 = *(const float2*)(W + (size_t)(k+0)*D);
                    float2 wA = *(const float2*)(W + (size_t)(k+1)*D);
                    float2 wB = *(const float2*)(W + (size_t)(k+2)*D);
                    float2 wC = *(const float2*)(W + (size_t)(k+3)*D);
                    acc.x = fmaf(x4.x, w0.x, acc.x); acc.y = fmaf(x4.x, w0.y, acc.y);
                    acc.x = fmaf(x4.y, wA.x, acc.x); acc.y = fmaf(x4.y, wA.y, acc.y);
                    acc.x = fmaf(x4.z, wB.x, acc.x); acc.y = fmaf(x4.z, wB.y, acc.y);
                    acc.x = fmaf(x4.w, wC.x, acc.x); acc.y = fmaf(x4.w, wC.y, acc.y);
                }
                *(float2*)(pr + h*512 + 2*p) = acc;
            }
            __syncthreads();
            // ---- combine + bias + residual + LN2 -> xv ----------------------
            {
                float u3 = 0.f;
                if (tid < D)
                    u3 = pr[tid] + pr[512+tid] + pr[1024+tid] + pr[1536+tid]
                       + b2[l*D + tid] + zv[tid];
                float s  = wred(tid < D ? u3 : 0.f);
                float sq = wred(tid < D ? u3*u3 : 0.f);
                if (lane == 0){ red[wave] = s; red[16+wave] = sq; }
                __syncthreads();
                s = 0.f; sq = 0.f;
                #pragma unroll
                for (int w = 0; w < 16; w++){ s += red[w]; sq += red[16+w]; }
                float mu = s*(1.f/D), rs = rsqrtf(sq*(1.f/D) - mu*mu + 1e-5f);
                if (tid < D)
                    xv[tid] = (u3 - mu)*rs*lng[(l*3+2)*D + tid] + lnb[(l*3+2)*D + tid];
            }
            __syncthreads();
        }

        // ---- logits: 4 cols/thread (2*tid,2*tid+1, +2048,+2049), full K ----
        float2 accA, accB;
        {
            const float* WA = outw + 2*tid;
            const float* WB = outw + 2048 + 2*tid;
            accA = *(const float2*)(outb + 2*tid);
            accB = *(const float2*)(outb + 2048 + 2*tid);
            #pragma unroll 2
            for (int k = 0; k < D; k += 2){
                float2 x2 = *(const float2*)(xv + k);
                float2 a0 = *(const float2*)(WA + (size_t)(k+0)*V);
                float2 a1 = *(const float2*)(WA + (size_t)(k+1)*V);
                float2 c0 = *(const float2*)(WB + (size_t)(k+0)*V);
                float2 c1 = *(const float2*)(WB + (size_t)(k+1)*V);
                accA.x = fmaf(x2.x, a0.x, accA.x); accA.y = fmaf(x2.x, a0.y, accA.y);
                accA.x = fmaf(x2.y, a1.x, accA.x); accA.y = fmaf(x2.y, a1.y, accA.y);
                accB.x = fmaf(x2.x, c0.x, accB.x); accB.y = fmaf(x2.x, c0.y, accB.y);
                accB.x = fmaf(x2.y, c1.x, accB.x); accB.y = fmaf(x2.y, c1.y, accB.y);
            }
        }
        // ---- argmax (first-index tie-break) + softmax ----------------------
        int i0 = 2*tid;
        float m = accA.x; int mi = i0;
        if (accA.y > m){ m = accA.y; mi = i0 + 1; }
        if (accB.x > m){ m = accB.x; mi = i0 + 2048; }
        if (accB.y > m){ m = accB.y; mi = i0 + 2049; }
        #pragma unroll
        for (int o = 32; o > 0; o >>= 1){
            float om = __shfl_xor(m, o, 64);
            int   oi = __shfl_xor(mi, o, 64);
            if (om > m || (om == m && oi < mi)){ m = om; mi = oi; }
        }
        if (lane == 0){ red[wave] = m; redI[wave] = mi; }
        __syncthreads();
        m = red[0]; mi = redI[0];
        #pragma unroll
        for (int w = 1; w < 16; w++)
            if (red[w] > m || (red[w] == m && redI[w] < mi)){ m = red[w]; mi = redI[w]; }
        float e0 = expf(accA.x - m), e1 = expf(accA.y - m);
        float e2 = expf(accB.x - m), e3 = expf(accB.y - m);
        float s = wred(e0 + e1 + e2 + e3);
        if (lane == 0) red[32 + wave] = s;
        __syncthreads();
        s = 0.f;
        #pragma unroll
        for (int w = 0; w < 16; w++) s += red[32 + w];
        float inv = 1.f / s;
        float* orow = out + ((size_t)b*T + t)*V;
        *(float2*)(orow + i0)        = make_float2(e0*inv, e1*inv);
        *(float2*)(orow + i0 + 2048) = make_float2(e2*inv, e3*inv);
        tok = mi;   // every thread derived the same argmax; no sync needed:
                    // next xv write is ordered by the top-of-step barrier
    }
}

// ---------------------------------------------------------------------------
extern "C" void kernel_launch(void* const* d_in, const int* in_sizes, int n_in,
                              void* d_out, int out_size, void* d_ws, size_t ws_size,
                              hipStream_t stream)
{
    fp prot = (fp)d_in[0];
    const int* itok = (const int*)d_in[1];
    fp p1w=(fp)d_in[2], p1b=(fp)d_in[3], p2w=(fp)d_in[4], p2b=(fp)d_in[5];
    fp emb=(fp)d_in[6], saw=(fp)d_in[7], sab=(fp)d_in[8];
    fp caw=(fp)d_in[9], cab=(fp)d_in[10];
    fp w1=(fp)d_in[11], b1=(fp)d_in[12], w2=(fp)d_in[13], b2=(fp)d_in[14];
    fp lng=(fp)d_in[15], lnb=(fp)d_in[16];
    fp outw=(fp)d_in[17], outb=(fp)d_in[18], pe=(fp)d_in[19];

    char* w = (char*)d_ws;
    float* wfold = (float*)w;  w += (size_t)4*D*D*4;   // 4 MB
    float* bfold = (float*)w;  w += 4*D*4;
    float* ca_o  = (float*)w;  w += 4*B*D*4;

    float* out = (float*)d_out;

    k_setup_mem<<<64, 256, 0, stream>>>(prot, p1w, p1b, p2w, p2b, caw, cab, ca_o);
    k_fold_sa<<<256, 256, 0, stream>>>(saw, sab, wfold, bfold);
    k_row_decode<<<B, 1024, 0, stream>>>(
        wfold, bfold, ca_o, lng, lnb, itok, emb, pe,
        w1, b1, w2, b2, outw, outb, out);
}

// Round 4
// 44055.939 us; speedup vs baseline: 4.1348x; 1.9344x over previous
//
#include <hip/hip_runtime.h>

// DNADecoder: B=64,T=128,P=1024,D=512,F=2048,V=4096,L=4
// Persistent GEMM-phase decoder, 128 wgs x 256 thr (1 wg/CU, trivially
// co-resident). Weights amortized across all 64 rows per phase (GEMM, not
// GEMV). Cross-wg activations move as 8B float2 agent-scope (MALL-coherent)
// requests; LN computed once per row in tiny combine stages so every GEMM
// consumer reads only its k-slice. Barrier: single counter, 1 arrival + 1
// polling lane per wg (no poll storm), s_sleep backoff.

#define B 64
#define T 128
#define PP 1024
#define D 512
#define F 2048
#define V 4096
#define XP 20        // padded row stride of transposed LDS x-tiles
#define NWG 128      // persistent grid

typedef const float* fp;

static __device__ __forceinline__ float wred(float s){
    #pragma unroll
    for (int o = 32; o > 0; o >>= 1) s += __shfl_xor(s, o, 64);
    return s;
}

// ---- 8B agent-coherent accessors (sc0/sc1 path, bypasses non-coherent L2) --
static __device__ __forceinline__ float2 gload2(const float* p){
    unsigned long long u = __hip_atomic_load((const unsigned long long*)p,
                             __ATOMIC_RELAXED, __HIP_MEMORY_SCOPE_AGENT);
    union { unsigned long long u; float2 f; } c; c.u = u; return c.f;
}
static __device__ __forceinline__ void gstore2(float* p, float2 v){
    union { unsigned long long u; float2 f; } c; c.f = v;
    __hip_atomic_store((unsigned long long*)p, c.u,
                       __ATOMIC_RELAXED, __HIP_MEMORY_SCOPE_AGENT);
}
static __device__ __forceinline__ int gloadi(const int* p){
    return __hip_atomic_load(p, __ATOMIC_RELAXED, __HIP_MEMORY_SCOPE_AGENT);
}
static __device__ __forceinline__ void gstorei(int* p, int v){
    __hip_atomic_store(p, v, __ATOMIC_RELAXED, __HIP_MEMORY_SCOPE_AGENT);
}

// ---- grid barrier: ONE counter; 1 fetch_add + 1 polling lane per wg --------
static __device__ __forceinline__ void gsync(unsigned* bar, unsigned ph){
    __syncthreads();                         // drains vmcnt(0) per wave
    if (threadIdx.x == 0){
        __hip_atomic_fetch_add(bar, 1u, __ATOMIC_RELAXED,
                               __HIP_MEMORY_SCOPE_AGENT);
        unsigned tgt = ph * (unsigned)NWG;
        while (__hip_atomic_load(bar, __ATOMIC_RELAXED,
                                 __HIP_MEMORY_SCOPE_AGENT) < tgt)
            __builtin_amdgcn_s_sleep(4);
    }
    __syncthreads();
}

__global__ void k_init(unsigned* bar){ bar[threadIdx.x] = 0u; }

// ---------------- setup: protein -> mem1 -> per-layer cross-attn constant ----
__global__ __launch_bounds__(256) void k_setup_mem(
    fp prot, fp p1w, fp p1b, fp p2w, fp p2b,
    fp caw, fp cab, float* ca_out)
{
    __shared__ float xp[PP];
    __shared__ float hr[PP];
    __shared__ float m1[D];
    __shared__ float tv[D];
    int b = blockIdx.x, tid = threadIdx.x;
    for (int i = tid; i < PP; i += 256) xp[i] = prot[b*PP + i];
    __syncthreads();
    for (int c = tid; c < 1024; c += 256){
        float acc = p1b[c];
        for (int k = 0; k < PP; k++) acc = fmaf(xp[k], p1w[k*1024 + c], acc);
        hr[c] = fmaxf(acc, 0.f);
    }
    __syncthreads();
    for (int c = tid; c < D; c += 256){
        float acc = p2b[c];
        for (int k = 0; k < 1024; k++) acc = fmaf(hr[k], p2w[k*D + c], acc);
        m1[c] = acc;
    }
    __syncthreads();
    for (int l = 0; l < 4; l++){
        const float* wv = caw + (size_t)(l*4 + 2)*D*D;
        const float* bv = cab + (l*4 + 2)*D;
        for (int c = tid; c < D; c += 256){
            float acc = bv[c];
            for (int k = 0; k < D; k++) acc = fmaf(m1[k], wv[k*D + c], acc);
            tv[c] = acc;
        }
        __syncthreads();
        const float* wo = caw + (size_t)(l*4 + 3)*D*D;
        const float* bo = cab + (l*4 + 3)*D;
        for (int c = tid; c < D; c += 256){
            float acc = bo[c];
            for (int k = 0; k < D; k++) acc = fmaf(tv[k], wo[k*D + c], acc);
            ca_out[(l*B + b)*D + c] = acc;
        }
        __syncthreads();
    }
}

// ---------------- setup: fold self-attn  Wfold = Wv@Wo + I, bfold = bv@Wo+bo --
__global__ __launch_bounds__(256) void k_fold_sa(
    fp saw, fp sab, float* wfold, float* bfold)
{
    int l = blockIdx.x >> 6;
    int kb = blockIdx.x & 63;
    int tid = threadIdx.x;
    const float* Wv = saw + (size_t)(l*4 + 2)*D*D;
    const float* Wo = saw + (size_t)(l*4 + 3)*D*D;
    __shared__ float a[8][D];
    for (int i = tid; i < 8*D; i += 256){
        int r = i >> 9, m = i & 511;
        a[r][m] = Wv[(kb*8 + r)*D + m];
    }
    __syncthreads();
    for (int cc = 0; cc < 2; cc++){
        int c = tid + cc*256;
        float acc[8];
        #pragma unroll
        for (int r = 0; r < 8; r++) acc[r] = 0.f;
        for (int m = 0; m < D; m++){
            float w = Wo[m*D + c];
            #pragma unroll
            for (int r = 0; r < 8; r++) acc[r] = fmaf(a[r][m], w, acc[r]);
        }
        #pragma unroll
        for (int r = 0; r < 8; r++){
            int kg = kb*8 + r;
            wfold[((size_t)l*D + kg)*D + c] = acc[r] + (kg == c ? 1.f : 0.f);
        }
    }
    if (kb == 0){
        const float* bv = sab + (l*4 + 2)*D;
        const float* bo = sab + (l*4 + 3)*D;
        for (int c = tid; c < D; c += 256){
            float acc = bo[c];
            for (int m = 0; m < D; m++) acc = fmaf(bv[m], Wo[m*D + c], acc);
            bfold[l*D + c] = acc;
        }
    }
}

// ---- shared helpers for the persistent kernel ------------------------------

// transposed LDS x-tile: xt[k*XP + rr], 16 rows; filled from an agent tensor
static __device__ __forceinline__ void load_xt_agent(
    float* xt, const float* src, int ld, int r0, int k0, int K, int tid)
{
    int rr = tid >> 4, q = tid & 15;
    int per = K >> 4;                            // 16 (K=256) or 32 (K=512)
    const float* s = src + (size_t)(r0 + rr)*ld + k0 + q*per;
    float* xb = xt + rr;
    for (int j = 0; j < per; j += 2){
        float2 v = gload2(s + j);
        xb[(q*per + j)*XP]     = v.x;
        xb[(q*per + j + 1)*XP] = v.y;
    }
}

// [4 rows x 2 cols]/thread GEMM over K; W pre-offset to this lane's col pair
static __device__ __forceinline__ void gemm_body(
    const float* xt, const float* W, int ldw, int K, float2 a[4], int rb)
{
    const float* xc = xt + rb*4;
    #pragma unroll 8
    for (int k = 0; k < K; k++){
        float2 w = *(const float2*)(W + (size_t)k*ldw);
        float4 x4 = *(const float4*)(xc + (size_t)k*XP);
        a[0].x = fmaf(x4.x, w.x, a[0].x); a[0].y = fmaf(x4.x, w.y, a[0].y);
        a[1].x = fmaf(x4.y, w.x, a[1].x); a[1].y = fmaf(x4.y, w.y, a[1].y);
        a[2].x = fmaf(x4.z, w.x, a[2].x); a[2].y = fmaf(x4.z, w.y, a[2].y);
        a[3].x = fmaf(x4.w, w.x, a[3].x); a[3].y = fmaf(x4.w, w.y, a[3].y);
    }
}

// row stats (mu, rs) over a 512-vector; thread holds elements 2*tid, 2*tid+1
static __device__ __forceinline__ float2 rowstat(float v0, float v1,
                                                 float* red, int tid)
{
    __syncthreads();                             // protect red reuse
    float s = v0 + v1, sq = v0*v0 + v1*v1;
    s = wred(s); sq = wred(sq);
    int lane = tid & 63, wave = tid >> 6;
    if (lane == 0){ red[wave] = s; red[8 + wave] = sq; }
    __syncthreads();
    s  = red[0] + red[1] + red[2] + red[3];
    sq = red[8] + red[9] + red[10] + red[11];
    float mu = s*(1.f/512.f);
    float rs = rsqrtf(sq*(1.f/512.f) - mu*mu + 1e-5f);
    return make_float2(mu, rs);
}

// ---- stages ----------------------------------------------------------------

// u1p[ks] = x @ Wfold[l] (x = xf, or emb+pe at l==0); 32 wgs
static __device__ void st_sa(float* xt, const float* wfold, fp bfold,
                             const float* xf, const int* tsrc, fp emb, fp pe,
                             float* u1p, int l, int t, int bx, int tid)
{
    int cb = bx & 3, rbg = (bx >> 2) & 3, ks = bx >> 4;
    int r0 = rbg*16, k0 = ks*256;
    if (l == 0){
        int rr = tid >> 4, q = tid & 15;
        int tk = gloadi(tsrc + r0 + rr);
        const float* er = emb + (size_t)tk*D + k0 + q*16;
        const float* pp = pe + (size_t)t*D + k0 + q*16;
        #pragma unroll
        for (int j = 0; j < 16; j++)
            xt[(q*16 + j)*XP + rr] = er[j] + pp[j];
    } else {
        load_xt_agent(xt, xf, D, r0, k0, 256, tid);
    }
    __syncthreads();
    int lane = tid & 63, rb = tid >> 6;
    int c = cb*128 + lane*2;
    const float* W = wfold + (size_t)l*D*D + (size_t)k0*D + c;
    float2 bias = make_float2(0.f, 0.f);
    if (ks == 0) bias = *(const float2*)(bfold + (size_t)l*D + c);
    float2 a[4]; a[0]=a[1]=a[2]=a[3]=bias;
    gemm_body(xt, W, D, 256, a, rb);
    float* o = u1p + (size_t)ks*B*D;
    #pragma unroll
    for (int i = 0; i < 4; i++)
        gstore2(o + (size_t)(r0 + rb*4 + i)*D + c, a[i]);
}

// z = LN1( LN0(u1p0+u1p1) + ca ); 64 wgs, one row each
static __device__ void st_cz(float* red, const float* u1p, const float* ca_o,
                             fp lng, fp lnb, float* z, int l, int b, int tid)
{
    int d = tid*2;
    float2 p0 = gload2(u1p + (size_t)b*D + d);
    float2 p1 = gload2(u1p + (size_t)B*D + (size_t)b*D + d);
    float vx = p0.x + p1.x, vy = p0.y + p1.y;
    float2 st = rowstat(vx, vy, red, tid);
    const float* g0 = lng + (size_t)(l*3)*D;
    const float* b0 = lnb + (size_t)(l*3)*D;
    const float* ca = ca_o + ((size_t)l*B + b)*D;
    float zx = (vx - st.x)*st.y*g0[d]   + b0[d]   + ca[d];
    float zy = (vy - st.x)*st.y*g0[d+1] + b0[d+1] + ca[d+1];
    float2 s2 = rowstat(zx, zy, red, tid);
    const float* g1 = lng + (size_t)(l*3+1)*D;
    const float* b1 = lnb + (size_t)(l*3+1)*D;
    float2 zo;
    zo.x = (zx - s2.x)*s2.y*g1[d]   + b1[d];
    zo.y = (zy - s2.x)*s2.y*g1[d+1] + b1[d+1];
    gstore2(z + (size_t)b*D + d, zo);
}

// hp[ks] = z @ W1 (+b1 at ks==0); 128 wgs
static __device__ void st_f1(float* xt, const float* z, fp w1, fp b1,
                             float* hp, int l, int bx, int tid)
{
    int cb = bx & 15, rbg = (bx >> 4) & 3, ks = bx >> 6;
    int r0 = rbg*16, k0 = ks*256;
    load_xt_agent(xt, z, D, r0, k0, 256, tid);
    __syncthreads();
    int lane = tid & 63, rb = tid >> 6;
    int c = cb*128 + lane*2;
    const float* W = w1 + (size_t)l*D*F + (size_t)k0*F + c;
    float2 bias = make_float2(0.f, 0.f);
    if (ks == 0) bias = *(const float2*)(b1 + (size_t)l*F + c);
    float2 a[4]; a[0]=a[1]=a[2]=a[3]=bias;
    gemm_body(xt, W, F, 256, a, rb);
    float* o = hp + (size_t)ks*B*F;
    #pragma unroll
    for (int i = 0; i < 4; i++)
        gstore2(o + (size_t)(r0 + rb*4 + i)*F + c, a[i]);
}

// u3p[kh] = relu(hp0+hp1)@W2 (+b2+z at kh==0); 64 wgs
static __device__ void st_f2(float* xt, const float* hp, const float* z,
                             fp w2, fp b2, float* u3p, int l, int bx, int tid)
{
    int cb = bx & 3, rbg = (bx >> 2) & 3, kh = bx >> 4;
    int r0 = rbg*16, k0 = kh*512;
    {
        int rr = tid >> 4, q = tid & 15;
        size_t base = (size_t)(r0 + rr)*F + k0 + q*32;
        float* xb = xt + rr;
        #pragma unroll
        for (int j = 0; j < 32; j += 2){
            float2 aa = gload2(hp + base + j);
            float2 bb = gload2(hp + (size_t)B*F + base + j);
            xb[(q*32 + j)*XP]     = fmaxf(aa.x + bb.x, 0.f);
            xb[(q*32 + j + 1)*XP] = fmaxf(aa.y + bb.y, 0.f);
        }
    }
    __syncthreads();
    int lane = tid & 63, rb = tid >> 6;
    int c = cb*128 + lane*2;
    const float* W = w2 + (size_t)l*F*D + (size_t)k0*D + c;
    float2 a[4];
    if (kh == 0){
        float2 bb = *(const float2*)(b2 + (size_t)l*D + c);
        #pragma unroll
        for (int i = 0; i < 4; i++){
            float2 zz = gload2(z + (size_t)(r0 + rb*4 + i)*D + c);
            a[i] = make_float2(bb.x + zz.x, bb.y + zz.y);
        }
    } else {
        a[0]=a[1]=a[2]=a[3]=make_float2(0.f, 0.f);
    }
    gemm_body(xt, W, D, 512, a, rb);
    float* o = u3p + (size_t)kh*B*D;
    #pragma unroll
    for (int i = 0; i < 4; i++)
        gstore2(o + (size_t)(r0 + rb*4 + i)*D + c, a[i]);
}

// xf = LN2(sum of 4 u3 partials); 64 wgs, one row each
static __device__ void st_cxf(float* red, const float* u3p, fp lng, fp lnb,
                              float* xf, int l, int b, int tid)
{
    int d = tid*2;
    float vx = 0.f, vy = 0.f;
    #pragma unroll
    for (int p = 0; p < 4; p++){
        float2 pp = gload2(u3p + (size_t)p*B*D + (size_t)b*D + d);
        vx += pp.x; vy += pp.y;
    }
    float2 st = rowstat(vx, vy, red, tid);
    const float* g  = lng + (size_t)(l*3+2)*D;
    const float* bb = lnb + (size_t)(l*3+2)*D;
    float2 o;
    o.x = (vx - st.x)*st.y*g[d]   + bb[d];
    o.y = (vy - st.x)*st.y*g[d+1] + bb[d+1];
    gstore2(xf + (size_t)b*D + d, o);
}

// lgt = xf @ outw + outb (full K, no partials); 128 wgs
static __device__ void st_lgt(float* xt, const float* xf, fp outw, fp outb,
                              float* lg, int bx, int tid)
{
    int cb = bx & 31, rbg = bx >> 5;
    int r0 = rbg*16;
    load_xt_agent(xt, xf, D, r0, 0, 512, tid);
    __syncthreads();
    int lane = tid & 63, rb = tid >> 6;
    int c = cb*128 + lane*2;
    const float* W = outw + c;
    float2 bias = *(const float2*)(outb + c);
    float2 a[4]; a[0]=a[1]=a[2]=a[3]=bias;
    gemm_body(xt, W, V, 512, a, rb);
    #pragma unroll
    for (int i = 0; i < 4; i++)
        gstore2(lg + (size_t)(r0 + rb*4 + i)*V + c, a[i]);
}

// softmax+argmax of one row; 64 wgs
static __device__ void st_fin(float* red, const float* lg, float* out,
                              int* tok, int t, int b, int tid)
{
    int lane = tid & 63, wave = tid >> 6;
    int* redI = (int*)(red + 24);
    float2 v[8];
    #pragma unroll
    for (int ii = 0; ii < 8; ii++)
        v[ii] = gload2(lg + (size_t)b*V + (size_t)(tid + ii*256)*2);
    float m = -3.4e38f; int mi = 0;
    #pragma unroll
    for (int ii = 0; ii < 8; ii++){
        int i0 = (tid + ii*256)*2;
        if (v[ii].x > m){ m = v[ii].x; mi = i0; }
        if (v[ii].y > m){ m = v[ii].y; mi = i0 + 1; }
    }
    #pragma unroll
    for (int o = 32; o > 0; o >>= 1){
        float om = __shfl_xor(m, o, 64);
        int   oi = __shfl_xor(mi, o, 64);
        if (om > m || (om == m && oi < mi)){ m = om; mi = oi; }
    }
    __syncthreads();
    if (lane == 0){ red[wave] = m; redI[wave] = mi; }
    __syncthreads();
    m = red[0]; mi = redI[0];
    #pragma unroll
    for (int w = 1; w < 4; w++)
        if (red[w] > m || (red[w] == m && redI[w] < mi)){ m = red[w]; mi = redI[w]; }
    float s = 0.f;
    float2 e[8];
    #pragma unroll
    for (int ii = 0; ii < 8; ii++){
        e[ii].x = expf(v[ii].x - m);
        e[ii].y = expf(v[ii].y - m);
        s += e[ii].x + e[ii].y;
    }
    s = wred(s);
    if (lane == 0) red[16 + wave] = s;
    __syncthreads();
    float inv = 1.f / (red[16] + red[17] + red[18] + red[19]);
    float* orow = out + ((size_t)b*T + t)*V;
    #pragma unroll
    for (int ii = 0; ii < 8; ii++){
        int idx = tid + ii*256;
        float2 w2 = make_float2(e[ii].x*inv, e[ii].y*inv);
        *(float2*)(orow + (size_t)idx*2) = w2;
    }
    if (tid == 0) gstorei(tok + b, mi);
}

// ---------------- the persistent decode kernel -------------------------------
__global__ __launch_bounds__(256, 2) void k_decode(
    const float* wfold, const float* bfold, const float* ca_o,
    fp lng, fp lnb, const int* itok, fp emb, fp pe,
    fp w1, fp b1, fp w2, fp b2, fp outw, fp outb,
    float* u1p, float* z, float* hp, float* u3p, float* xf, float* lg,
    int* tok, unsigned* bar, float* out)
{
    __shared__ float smem[512*XP + 64];     // 41.2 KB: xt + reduction scratch
    float* xt  = smem;
    float* red = smem + 512*XP;
    int bx = blockIdx.x, tid = threadIdx.x;
    unsigned ph = 0;
    for (int t = 0; t < T; t++){
        const int* tsrc = (t == 0) ? itok : tok;
        for (int l = 0; l < 4; l++){
            if (bx < 32)  st_sa (xt, wfold, bfold, xf, tsrc, emb, pe, u1p, l, t, bx, tid);
            ph++; gsync(bar, ph);
            if (bx < 64)  st_cz (red, u1p, ca_o, lng, lnb, z, l, bx, tid);
            ph++; gsync(bar, ph);
            if (bx < 128) st_f1 (xt, z, w1, b1, hp, l, bx, tid);
            ph++; gsync(bar, ph);
            if (bx < 64)  st_f2 (xt, hp, z, w2, b2, u3p, l, bx, tid);
            ph++; gsync(bar, ph);
            if (bx < 64)  st_cxf(red, u3p, lng, lnb, xf, l, bx, tid);
            ph++; gsync(bar, ph);
        }
        if (bx < 128) st_lgt(xt, xf, outw, outb, lg, bx, tid);
        ph++; gsync(bar, ph);
        if (bx < 64)  st_fin(red, lg, out, tok, t, bx, tid);
        ph++; gsync(bar, ph);
    }
}

// ---------------------------------------------------------------------------
extern "C" void kernel_launch(void* const* d_in, const int* in_sizes, int n_in,
                              void* d_out, int out_size, void* d_ws, size_t ws_size,
                              hipStream_t stream)
{
    fp prot = (fp)d_in[0];
    const int* itok = (const int*)d_in[1];
    fp p1w=(fp)d_in[2], p1b=(fp)d_in[3], p2w=(fp)d_in[4], p2b=(fp)d_in[5];
    fp emb=(fp)d_in[6], saw=(fp)d_in[7], sab=(fp)d_in[8];
    fp caw=(fp)d_in[9], cab=(fp)d_in[10];
    fp w1=(fp)d_in[11], b1=(fp)d_in[12], w2=(fp)d_in[13], b2=(fp)d_in[14];
    fp lng=(fp)d_in[15], lnb=(fp)d_in[16];
    fp outw=(fp)d_in[17], outb=(fp)d_in[18], pe=(fp)d_in[19];

    char* w = (char*)d_ws;
    float* wfold = (float*)w;  w += (size_t)4*D*D*4;   // 4 MB
    float* bfold = (float*)w;  w += 4*D*4;
    float* ca_o  = (float*)w;  w += 4*B*D*4;
    float* u1p   = (float*)w;  w += 2*B*D*4;           // 2 K-partials
    float* z     = (float*)w;  w += B*D*4;
    float* hp    = (float*)w;  w += 2*B*F*4;           // 2 K-partials
    float* u3p   = (float*)w;  w += 4*B*D*4;           // 4 K-partials
    float* xf    = (float*)w;  w += B*D*4;
    float* lg    = (float*)w;  w += B*V*4;
    int*   tok   = (int*)w;    w += 256;
    unsigned* bar = (unsigned*)w; w += 64*4;

    float* out = (float*)d_out;

    k_setup_mem<<<64, 256, 0, stream>>>(prot, p1w, p1b, p2w, p2b, caw, cab, ca_o);
    k_fold_sa<<<256, 256, 0, stream>>>(saw, sab, wfold, bfold);
    k_init<<<1, 64, 0, stream>>>(bar);

    k_decode<<<NWG, 256, 0, stream>>>(
        wfold, bfold, ca_o, lng, lnb, itok, emb, pe,
        w1, b1, w2, b2, outw, outb,
        u1p, z, hp, u3p, xf, lg, tok, bar, out);
}